// Round 3
// baseline (9082.543 us; speedup 1.0000x reference)
//
#include <hip/hip_runtime.h>
#include <stdint.h>

#define B 32
#define S 64
#define T 32
#define E 300
#define HE 256
#define HD 512
#define VD 50000
#define GE 768
#define GD 1536
#define CATN 812
#define SOS 2
#define EOS 3

// ---------------- ws layout (float offsets) ----------------
#define SZ_WIHT3   (E*HE*3)
#define SZ_WHHT3   (HE*HE*3)
#define SZ_WATTNT4 (CATN*HD)
#define SZ_WIHDT3  (CATN*HD*3)
#define SZ_WHHDT3  (HD*HD*3)
#define SZ_GI      (S*B*HE*3)
#define SZ_ENCOUT  (B*S*HD)

constexpr size_t OFF_WIHT3F  = 0;
constexpr size_t OFF_WIHT3B  = OFF_WIHT3F + SZ_WIHT3 + 4;
constexpr size_t OFF_WHHT3F  = OFF_WIHT3B + SZ_WIHT3 + 4;
constexpr size_t OFF_WHHT3B  = OFF_WHHT3F + SZ_WHHT3 + 4;
constexpr size_t OFF_WATTNT4 = OFF_WHHT3B + SZ_WHHT3 + 4;
constexpr size_t OFF_WIHDT3  = OFF_WATTNT4 + SZ_WATTNT4;
constexpr size_t OFF_WHHDT3  = OFF_WIHDT3 + SZ_WIHDT3 + 4;
constexpr size_t OFF_GIF     = OFF_WHHDT3 + SZ_WHHDT3 + 4;
constexpr size_t OFF_GIB     = OFF_GIF + SZ_GI + 4;
constexpr size_t OFF_ENCOUT  = OFF_GIB + SZ_GI + 4;
constexpr size_t OFF_HBUF    = OFF_ENCOUT + SZ_ENCOUT;     // ping-pong: 2 * B*HD
constexpr size_t OFF_QBUF    = OFF_HBUF + 2*B*HD;
constexpr size_t OFF_CTXBUF  = OFF_QBUF + B*HD;
constexpr size_t OFF_EXPSUM  = OFF_CTXBUF + B*HD;          // [T][B]
constexpr size_t OFF_LSE     = OFF_EXPSUM + T*B;           // [T][B]
constexpr size_t OFF_PACKED  = OFF_LSE + T*B;              // u64 [T][B]
constexpr size_t OFF_WOUTT   = OFF_PACKED + 2*T*B;         // [HD][VD] transposed Wout

// ---------------- d_out layout ----------------
constexpr size_t O_IDX  = (size_t)B*T*VD;
constexpr size_t O_MASK = O_IDX + B*T;
constexpr size_t O_ATT  = O_MASK + B*T;

struct __align__(4) f4u { float x, y, z, w; };
__device__ __forceinline__ f4u ld4u(const float* p) { return *(const f4u*)p; }

__device__ __forceinline__ float sigm(float x) { return 1.0f / (1.0f + __expf(-x)); }
__device__ __forceinline__ float tanhfast(float x) {
    float e = __expf(2.0f * fminf(x, 15.0f));
    return (e - 1.0f) / (e + 1.0f);
}

// ---------------- K0: weight repack + scratch zero ----------------
__global__ __launch_bounds__(256) void k_prep(
    const float* __restrict__ Wihf, const float* __restrict__ Whhf,
    const float* __restrict__ Wihb, const float* __restrict__ Whhb,
    const float* __restrict__ Wihd, const float* __restrict__ Whhd,
    const float* __restrict__ Wattn, float* __restrict__ ws)
{
    const size_t NWIH = (size_t)GE * E;
    const size_t NWHH = (size_t)GE * HE;
    const size_t NATT = (size_t)HD * CATN;
    const size_t NWID = (size_t)GD * CATN;
    const size_t NWHD = (size_t)GD * HD;
    size_t i = (size_t)blockIdx.x * 256 + threadIdx.x;

    if (i < 2 * NWIH) {
        int d = i >= NWIH;
        size_t r = i - (d ? NWIH : 0);
        int row = (int)(r / E), k = (int)(r - (size_t)row * E);
        int g = row >> 8, j = row & 255;
        const float* src = d ? Wihb : Wihf;
        ws[(d ? OFF_WIHT3B : OFF_WIHT3F) + ((size_t)k * HE + j) * 3 + g] = src[r];
        return;
    }
    i -= 2 * NWIH;
    if (i < 2 * NWHH) {
        int d = i >= NWHH;
        size_t r = i - (d ? NWHH : 0);
        int row = (int)(r / HE), k = (int)(r & (HE - 1));
        int g = row >> 8, j = row & 255;
        const float* src = d ? Whhb : Whhf;
        ws[(d ? OFF_WHHT3B : OFF_WHHT3F) + ((size_t)k * HE + j) * 3 + g] = src[r];
        return;
    }
    i -= 2 * NWHH;
    if (i < NATT) {
        int row = (int)(i / CATN), k = (int)(i - (size_t)row * CATN);
        ws[OFF_WATTNT4 + (((size_t)(k >> 2) * HD + row) << 2) + (k & 3)] = Wattn[i];
        return;
    }
    i -= NATT;
    if (i < NWID) {
        int row = (int)(i / CATN), k = (int)(i - (size_t)row * CATN);
        int g = row >> 9, j = row & 511;
        ws[OFF_WIHDT3 + ((size_t)k * HD + j) * 3 + g] = Wihd[i];
        return;
    }
    i -= NWID;
    if (i < NWHD) {
        int row = (int)(i / HD), k = (int)(i & (HD - 1));
        int g = row >> 9, j = row & 511;
        ws[OFF_WHHDT3 + ((size_t)k * HD + j) * 3 + g] = Whhd[i];
        return;
    }
    i -= NWHD;
    if (i < 4096) ws[OFF_EXPSUM + i] = 0.0f;   // expsum + lse + packedmax
}

// ---------------- K0b: transpose Wout [VD][HD] -> WoutT [HD][VD] ----------------
__global__ __launch_bounds__(256) void k_transp(
    const float* __restrict__ Wout, float* __restrict__ ws)
{
    __shared__ float tile[64][65];
    int k0 = blockIdx.x * 64, v0 = blockIdx.y * 64;
    int c = threadIdx.x & 63, r0 = threadIdx.x >> 6;
#pragma unroll
    for (int rr = 0; rr < 16; rr++) {
        int r = r0 * 16 + rr;
        int v = v0 + r;
        tile[r][c] = (v < VD) ? Wout[(size_t)v * HD + k0 + c] : 0.f;
    }
    __syncthreads();
    float* WT = ws + OFF_WOUTT;
#pragma unroll
    for (int rr = 0; rr < 16; rr++) {
        int r = r0 * 16 + rr;                 // output k offset
        int v = v0 + c;
        if (v < VD) WT[(size_t)(k0 + r) * VD + v] = tile[c][r];
    }
}

// ---------------- K1: encoder input gates ----------------
__global__ __launch_bounds__(256) void k_enc_gi(
    const int* __restrict__ data, const float* __restrict__ emb_enc,
    const float* __restrict__ bihf, const float* __restrict__ bihb,
    float* __restrict__ ws)
{
    int s = blockIdx.x, dir = blockIdx.y, b0 = blockIdx.z * 16;
    int tid = threadIdx.x;
    __shared__ float xT[E * 16];
    int s_eff = dir ? (S - 1 - s) : s;
    for (int idx = tid; idx < 16 * E; idx += 256) {
        int bb = idx / E, k = idx - bb * E;
        int tok = data[(b0 + bb) * S + s_eff];
        xT[k * 16 + bb] = emb_enc[(size_t)tok * E + k];
    }
    __syncthreads();
    const float* W3 = ws + (dir ? OFF_WIHT3B : OFF_WIHT3F);
    const float* bih = dir ? bihb : bihf;
    int j = tid;
    float aR[16], aZ[16], aN[16];
#pragma unroll
    for (int bb = 0; bb < 16; bb++) { aR[bb] = 0.f; aZ[bb] = 0.f; aN[bb] = 0.f; }
    for (int k = 0; k < E; k++) {
        f4u w = ld4u(W3 + ((size_t)k * HE + j) * 3);
        const float* xk = &xT[k * 16];
#pragma unroll
        for (int bb = 0; bb < 16; bb++) {
            float x = xk[bb];
            aR[bb] += x * w.x; aZ[bb] += x * w.y; aN[bb] += x * w.z;
        }
    }
    float br = bih[j], bz = bih[HE + j], bn = bih[2 * HE + j];
    float* gi = ws + (dir ? OFF_GIB : OFF_GIF);
#pragma unroll
    for (int bb = 0; bb < 16; bb++) {
        size_t base = (((size_t)s * B + b0 + bb) * HE + j) * 3;
        gi[base + 0] = aR[bb] + br;
        gi[base + 1] = aZ[bb] + bz;
        gi[base + 2] = aN[bb] + bn;
    }
}

// ---------------- K2: encoder recurrence — 4 batch rows per block ----------------
// grid (8, 2), 1024 threads: j = tid&255, kc = tid>>8 (64 k each)
__global__ __launch_bounds__(1024) void k_enc_rec(
    const float* __restrict__ bhhf, const float* __restrict__ bhhb,
    float* __restrict__ ws)
{
    int b0 = blockIdx.x * 4, dir = blockIdx.y;
    int tid = threadIdx.x;
    int j = tid & 255, kc = tid >> 8;
    __shared__ float h[2][4][HE];            // ping-pong
    __shared__ float part[4][4][3][HE];      // [kc][b][gate][j]  48 KB
    h[0][tid >> 8][tid & 255] = 0.f;
    __syncthreads();
    const float* W3 = ws + (dir ? OFF_WHHT3B : OFF_WHHT3F);
    const float* gi = ws + (dir ? OFF_GIB : OFF_GIF);
    const float* bhh = dir ? bhhb : bhhf;
    float* enc = ws + OFF_ENCOUT;
    float br = bhh[j], bz = bhh[HE + j], bn = bhh[2 * HE + j];
    const float* Wp = W3 + ((size_t)(kc * 64) * HE + j) * 3;
    for (int s = 0; s < S; s++) {
        int cur = s & 1, nxt = cur ^ 1;
        float ar[4], az[4], an[4];
#pragma unroll
        for (int bb = 0; bb < 4; bb++) { ar[bb] = 0.f; az[bb] = 0.f; an[bb] = 0.f; }
#pragma unroll 2
        for (int k4 = 0; k4 < 16; k4++) {
            float4 h4[4];
#pragma unroll
            for (int bb = 0; bb < 4; bb++)
                h4[bb] = *(const float4*)&h[cur][bb][kc * 64 + k4 * 4];
#pragma unroll
            for (int kk = 0; kk < 4; kk++) {
                f4u w = ld4u(Wp + ((size_t)(k4 * 4 + kk) * HE) * 3);
#pragma unroll
                for (int bb = 0; bb < 4; bb++) {
                    float hv = (kk == 0) ? h4[bb].x : (kk == 1) ? h4[bb].y
                             : (kk == 2) ? h4[bb].z : h4[bb].w;
                    ar[bb] += hv * w.x; az[bb] += hv * w.y; an[bb] += hv * w.z;
                }
            }
        }
#pragma unroll
        for (int bb = 0; bb < 4; bb++) {
            part[kc][bb][0][j] = ar[bb];
            part[kc][bb][1][j] = az[bb];
            part[kc][bb][2][j] = an[bb];
        }
        __syncthreads();
        // reduce phase: thread (bb = kc, j)
        {
            int bb = kc;
            float sgr = part[0][bb][0][j] + part[1][bb][0][j] + part[2][bb][0][j] + part[3][bb][0][j] + br;
            float sgz = part[0][bb][1][j] + part[1][bb][1][j] + part[2][bb][1][j] + part[3][bb][1][j] + bz;
            float sgn = part[0][bb][2][j] + part[1][bb][2][j] + part[2][bb][2][j] + part[3][bb][2][j] + bn;
            f4u g = ld4u(gi + (((size_t)s * B + b0 + bb) * HE + j) * 3);
            float hold = h[cur][bb][j];
            float r = sigm(g.x + sgr);
            float z = sigm(g.y + sgz);
            float n = tanhfast(g.z + r * sgn);
            float hn = (1.f - z) * n + z * hold;
            h[nxt][bb][j] = hn;
            int s_store = dir ? (S - 1 - s) : s;
            enc[((size_t)(b0 + bb) * S + s_store) * HD + dir * HE + j] = hn;
            if (s == S - 1) ws[OFF_HBUF + (size_t)(b0 + bb) * HD + dir * HE + j] = hn;
        }
        __syncthreads();
    }
}

__device__ __forceinline__ int decode_inp(const float* ws, int t, int b) {
    if (t == 0) return SOS;
    const unsigned long long* pm = (const unsigned long long*)(ws + OFF_PACKED);
    unsigned long long p = pm[(size_t)(t - 1) * B + b];
    return (VD - 1) - (int)(unsigned)(p & 0xffffffffu);
}

// ---------------- Dq: q = cat(emb,h)@Wattn.T + battn — grid (16 jc, 4 bg) ----------------
__global__ __launch_bounds__(256) void k_dq(
    const float* __restrict__ emb_dec, const float* __restrict__ battn,
    float* __restrict__ ws, int t)
{
    int jc = blockIdx.x, b0 = blockIdx.y * 8;
    int tid = threadIdx.x;
    int jl = tid & 31, bb8 = tid >> 5;
    const float* hcur = ws + OFF_HBUF + (size_t)(t & 1) * B * HD;
    __shared__ float cat[8][816];
    for (int bb = 0; bb < 8; bb++) {
        int inp = decode_inp(ws, t, b0 + bb);
        const float* eb = emb_dec + (size_t)inp * E;
        const float* hb = hcur + (size_t)(b0 + bb) * HD;
        for (int k = tid; k < CATN; k += 256)
            cat[bb][k] = (k < E) ? eb[k] : hb[k - E];
    }
    __syncthreads();
    int j = jc * 32 + jl, b = b0 + bb8;
    float acc = battn[j];
    const float* W4 = ws + OFF_WATTNT4;
    for (int k4 = 0; k4 < CATN / 4; k4++) {
        float4 c4 = *(const float4*)&cat[bb8][k4 * 4];
        float4 w4 = *(const float4*)&W4[((size_t)k4 * HD + j) << 2];
        acc += c4.x * w4.x + c4.y * w4.y + c4.z * w4.z + c4.w * w4.w;
    }
    ws[OFF_QBUF + (size_t)b * HD + j] = acc;
}

// ---------------- Da: scores -> softmax -> ctx; block per b ----------------
__global__ __launch_bounds__(256) void k_attn(
    float* __restrict__ ws, float* __restrict__ out, int t)
{
    int b = blockIdx.x, tid = threadIdx.x;
    int wv = tid >> 6, lane = tid & 63;
    __shared__ float q[HD];
    __shared__ float scs[S];
    __shared__ float awl[S];
    const float* qb = ws + OFF_QBUF + (size_t)b * HD;
    for (int k = tid; k < HD; k += 256) q[k] = qb[k];
    __syncthreads();
    const float* encb = ws + OFF_ENCOUT + (size_t)b * S * HD;
    float4 qa = *(const float4*)&q[lane * 4];
    float4 qb4 = *(const float4*)&q[256 + lane * 4];
#pragma unroll 4
    for (int i = 0; i < 16; i++) {
        int s = wv * 16 + i;
        const float* e = encb + (size_t)s * HD;
        float4 ea = *(const float4*)&e[lane * 4];
        float4 eb = *(const float4*)&e[256 + lane * 4];
        float p = ea.x * qa.x + ea.y * qa.y + ea.z * qa.z + ea.w * qa.w
                + eb.x * qb4.x + eb.y * qb4.y + eb.z * qb4.z + eb.w * qb4.w;
        for (int off = 32; off; off >>= 1) p += __shfl_xor(p, off);
        if (lane == 0) scs[s] = p;
    }
    __syncthreads();
    if (tid < 64) {
        float v = scs[tid];
        float m = v;
        for (int off = 32; off; off >>= 1) m = fmaxf(m, __shfl_xor(m, off));
        float e = __expf(v - m);
        float sum = e;
        for (int off = 32; off; off >>= 1) sum += __shfl_xor(sum, off);
        float aw = e / sum;
        awl[tid] = aw;
        out[O_ATT + ((size_t)b * T + t) * S + tid] = aw;
    }
    __syncthreads();
    float* ctx = ws + OFF_CTXBUF + (size_t)b * HD;
    for (int j = tid; j < HD; j += 256) {
        float acc = 0.f;
        for (int ss = 0; ss < S; ss++) acc += awl[ss] * encb[(size_t)ss * HD + j];
        ctx[j] = acc;
    }
}

// ---------------- Dg: fused decoder GRU (giE + giC + gh + gates) ----------------
// grid (16 jc, 4 bg), 256 thr: thread = (j = jc*32 + tid&31, b = bg*8 + tid>>5)
__global__ __launch_bounds__(256) void k_dgru(
    const float* __restrict__ emb_dec,
    const float* __restrict__ bihd, const float* __restrict__ bhhd,
    float* __restrict__ ws, int t)
{
    int jc = blockIdx.x, b0 = blockIdx.y * 8;
    int tid = threadIdx.x;
    int jl = tid & 31, bb8 = tid >> 5;
    const float* hcur = ws + OFF_HBUF + (size_t)(t & 1) * B * HD;
    float* hnxt = ws + OFF_HBUF + (size_t)((t + 1) & 1) * B * HD;
    __shared__ float se[8][300];
    __shared__ float sh[8][512];
    __shared__ float sc[8][512];
    for (int bb = 0; bb < 8; bb++) {
        int inp = decode_inp(ws, t, b0 + bb);
        const float* eb = emb_dec + (size_t)inp * E;
        const float* hb = hcur + (size_t)(b0 + bb) * HD;
        const float* cx = ws + OFF_CTXBUF + (size_t)(b0 + bb) * HD;
        for (int k = tid; k < E; k += 256) se[bb][k] = eb[k];
        for (int k = tid; k < HD; k += 256) { sh[bb][k] = hb[k]; sc[bb][k] = cx[k]; }
    }
    __syncthreads();
    int j = jc * 32 + jl, b = b0 + bb8;
    float gr = bihd[j], gz = bihd[HD + j], gn = bihd[2 * HD + j];
    const float* W3i = ws + OFF_WIHDT3;
    for (int k4 = 0; k4 < E / 4; k4++) {
        float4 x4 = *(const float4*)&se[bb8][k4 * 4];
#pragma unroll
        for (int kk = 0; kk < 4; kk++) {
            f4u w = ld4u(W3i + ((size_t)(k4 * 4 + kk) * HD + j) * 3);
            float xv = (kk == 0) ? x4.x : (kk == 1) ? x4.y : (kk == 2) ? x4.z : x4.w;
            gr += xv * w.x; gz += xv * w.y; gn += xv * w.z;
        }
    }
    for (int k4 = 0; k4 < HD / 4; k4++) {
        float4 x4 = *(const float4*)&sc[bb8][k4 * 4];
#pragma unroll
        for (int kk = 0; kk < 4; kk++) {
            f4u w = ld4u(W3i + ((size_t)(E + k4 * 4 + kk) * HD + j) * 3);
            float xv = (kk == 0) ? x4.x : (kk == 1) ? x4.y : (kk == 2) ? x4.z : x4.w;
            gr += xv * w.x; gz += xv * w.y; gn += xv * w.z;
        }
    }
    float hr = bhhd[j], hz = bhhd[HD + j], hn_ = bhhd[2 * HD + j];
    const float* W3h = ws + OFF_WHHDT3;
    for (int k4 = 0; k4 < HD / 4; k4++) {
        float4 x4 = *(const float4*)&sh[bb8][k4 * 4];
#pragma unroll
        for (int kk = 0; kk < 4; kk++) {
            f4u w = ld4u(W3h + ((size_t)(k4 * 4 + kk) * HD + j) * 3);
            float xv = (kk == 0) ? x4.x : (kk == 1) ? x4.y : (kk == 2) ? x4.z : x4.w;
            hr += xv * w.x; hz += xv * w.y; hn_ += xv * w.z;
        }
    }
    float hold = sh[bb8][j];
    float r = sigm(gr + hr);
    float z = sigm(gz + hz);
    float n = tanhfast(gn + r * hn_);
    hnxt[(size_t)b * HD + j] = (1.f - z) * n + z * hold;
}

// ---------------- P1: logits via WoutT (coalesced) + argmax + expsum ----------------
// grid (196 v-tiles, 2 b-groups of 16), 256 thr, thread = one v
__global__ __launch_bounds__(256) void k_proj(
    const float* __restrict__ bout,
    float* __restrict__ ws, float* __restrict__ out, int t)
{
    int v = blockIdx.x * 256 + threadIdx.x;
    int b0 = blockIdx.y * 16;
    bool valid = v < VD;
    int vc = valid ? v : (VD - 1);
    __shared__ float hl[16 * 512];               // 32 KB
    __shared__ float red_e[4][16];
    __shared__ unsigned long long red_m[4][16];
    const float* hsrc = ws + OFF_HBUF + (size_t)((t + 1) & 1) * B * HD + (size_t)b0 * HD;
    for (int idx = threadIdx.x; idx < 16 * 512; idx += 256) hl[idx] = hsrc[idx];
    __syncthreads();

    float acc[16];
    float bo = bout[vc];
#pragma unroll
    for (int bb = 0; bb < 16; bb++) acc[bb] = bo;
    const float* WT = ws + OFF_WOUTT;
    for (int k4 = 0; k4 < HD / 4; k4++) {
        float w0 = WT[(size_t)(k4 * 4 + 0) * VD + vc];
        float w1 = WT[(size_t)(k4 * 4 + 1) * VD + vc];
        float w2 = WT[(size_t)(k4 * 4 + 2) * VD + vc];
        float w3 = WT[(size_t)(k4 * 4 + 3) * VD + vc];
#pragma unroll
        for (int bb = 0; bb < 16; bb++) {
            float4 h4 = *(const float4*)&hl[bb * 512 + k4 * 4];
            acc[bb] = fmaf(w0, h4.x, fmaf(w1, h4.y,
                      fmaf(w2, h4.z, fmaf(w3, h4.w, acc[bb]))));
        }
    }
    if (valid) {
#pragma unroll
        for (int bb = 0; bb < 16; bb++)
            out[((size_t)(b0 + bb) * T + t) * VD + v] = acc[bb];
    }
    int wv = threadIdx.x >> 6, lane = threadIdx.x & 63;
#pragma unroll
    for (int bb = 0; bb < 16; bb++) {
        float val = valid ? acc[bb] : -__builtin_inff();
        unsigned u = __float_as_uint(val);
        u = (u & 0x80000000u) ? ~u : (u | 0x80000000u);
        unsigned long long pk =
            ((unsigned long long)u << 32) | (unsigned)(valid ? (VD - 1 - v) : 0);
        float e = valid ? __expf(acc[bb]) : 0.f;
        for (int off = 32; off; off >>= 1) {
            unsigned long long o = __shfl_xor(pk, off);
            pk = (o > pk) ? o : pk;
            e += __shfl_xor(e, off);
        }
        if (lane == 0) { red_e[wv][bb] = e; red_m[wv][bb] = pk; }
    }
    __syncthreads();
    if (threadIdx.x < 16) {
        int bb = threadIdx.x;
        float e = red_e[0][bb] + red_e[1][bb] + red_e[2][bb] + red_e[3][bb];
        unsigned long long pk = red_m[0][bb];
        pk = red_m[1][bb] > pk ? red_m[1][bb] : pk;
        pk = red_m[2][bb] > pk ? red_m[2][bb] : pk;
        pk = red_m[3][bb] > pk ? red_m[3][bb] : pk;
        atomicAdd(ws + OFF_EXPSUM + (size_t)t * B + b0 + bb, e);
        atomicMax((unsigned long long*)(ws + OFF_PACKED) + (size_t)t * B + b0 + bb, pk);
    }
}

// ---------------- F2: idx, mask, lse ----------------
__global__ void k_fin_small(float* __restrict__ ws, float* __restrict__ out)
{
    int b = threadIdx.x;
    if (b >= B) return;
    const unsigned long long* pmax = (const unsigned long long*)(ws + OFF_PACKED);
    int eos = 0;
    for (int t = 0; t < T; t++) {
        unsigned long long p = pmax[(size_t)t * B + b];
        int v = (VD - 1) - (int)(unsigned)(p & 0xffffffffu);
        out[O_IDX + (size_t)b * T + t] = (float)v;
        if (v == EOS) eos++;
        out[O_MASK + (size_t)b * T + t] = (eos == 0) ? 1.f : 0.f;
        ws[OFF_LSE + (size_t)t * B + b] = logf(ws[OFF_EXPSUM + (size_t)t * B + b]);
    }
}

// ---------------- F1: logp = logits - lse ----------------
__global__ __launch_bounds__(256) void k_logp(
    const float* __restrict__ ws, float* __restrict__ out)
{
    size_t gid = (size_t)blockIdx.x * 256 + threadIdx.x;
    const size_t NQ = (size_t)B * T * (VD / 4);
    if (gid >= NQ) return;
    size_t row = gid / (VD / 4);
    int c4 = (int)(gid - row * (VD / 4));
    int b = (int)(row >> 5), t = (int)(row & 31);
    float L = ws[OFF_LSE + (size_t)t * B + b];
    float4* p = (float4*)(out + row * VD + (size_t)c4 * 4);
    float4 x = *p;
    x.x -= L; x.y -= L; x.z -= L; x.w -= L;
    *p = x;
}

extern "C" void kernel_launch(void* const* d_in, const int* in_sizes, int n_in,
                              void* d_out, int out_size, void* d_ws, size_t ws_size,
                              hipStream_t stream)
{
    (void)in_sizes; (void)n_in; (void)out_size; (void)ws_size;
    const int*   data    = (const int*)d_in[0];
    const float* emb_enc = (const float*)d_in[4];
    const float* emb_dec = (const float*)d_in[5];
    const float* Wihf    = (const float*)d_in[6];
    const float* Whhf    = (const float*)d_in[7];
    const float* bihf    = (const float*)d_in[8];
    const float* bhhf    = (const float*)d_in[9];
    const float* Wihb    = (const float*)d_in[10];
    const float* Whhb    = (const float*)d_in[11];
    const float* bihb    = (const float*)d_in[12];
    const float* bhhb    = (const float*)d_in[13];
    const float* Wihd    = (const float*)d_in[14];
    const float* Whhd    = (const float*)d_in[15];
    const float* bihd    = (const float*)d_in[16];
    const float* bhhd    = (const float*)d_in[17];
    const float* Wattn   = (const float*)d_in[18];
    const float* battn   = (const float*)d_in[19];
    const float* Wout    = (const float*)d_in[20];
    const float* bout    = (const float*)d_in[21];
    float* ws  = (float*)d_ws;
    float* out = (float*)d_out;

    k_prep<<<dim3(12920), dim3(256), 0, stream>>>(Wihf, Whhf, Wihb, Whhb,
                                                  Wihd, Whhd, Wattn, ws);
    k_transp<<<dim3(HD / 64, (VD + 63) / 64), dim3(256), 0, stream>>>(Wout, ws);
    k_enc_gi<<<dim3(S, 2, 2), dim3(256), 0, stream>>>(data, emb_enc, bihf, bihb, ws);
    k_enc_rec<<<dim3(8, 2), dim3(1024), 0, stream>>>(bhhf, bhhb, ws);

    for (int t = 0; t < T; t++) {
        k_dq<<<dim3(16, 4), dim3(256), 0, stream>>>(emb_dec, battn, ws, t);
        k_attn<<<dim3(B), dim3(256), 0, stream>>>(ws, out, t);
        k_dgru<<<dim3(16, 4), dim3(256), 0, stream>>>(emb_dec, bihd, bhhd, ws, t);
        k_proj<<<dim3(196, 2), dim3(256), 0, stream>>>(bout, ws, out, t);
    }
    k_fin_small<<<dim3(1), dim3(64), 0, stream>>>(ws, out);
    k_logp<<<dim3((B * T * (VD / 4) + 255) / 256), dim3(256), 0, stream>>>(ws, out);
}